// Round 16
// baseline (46.970 us; speedup 1.0000x reference)
//
#include <hip/hip_runtime.h>

// Depthwise temporal FIR (FW=64, SAME pad low=31/high=32), weight-norm +
// positivity clamp + bias. out[t,c] = b[c] + sum_f relu(w[f,c]/||w||) x[t-31+f,c]
//
// Round-16: R11 kernel (lane-pair tap split, 32-slot circular window,
// period-32 runtime loop, KTILE=128, c-blocks-fastest grid) with EXACTLY ONE
// change: the amdgpu_waves_per_eu attribute is REMOVED. Evidence R2-R15:
// every explicit occupancy hint pushed the allocator to a smaller-budget
// tier than its default (~102-128 arch VGPRs, cf. R2:104/R6:120); this
// structure's ~96-reg live set fits the DEFAULT tier -> no AGPR parking,
// no accvgpr mov inflation (the ~2x instruction bloat seen all session).

#define T_DIM 4096
#define C_DIM 4096
#define PAD_L 31
#define HT    32      // taps per lane (half filter)
#define KTILE 128     // outputs per lane-pair (time tile)
#define NPER  (KTILE / 32)

template <bool GUARD>
__device__ __forceinline__ void fir_body(const float* __restrict__ x,
                                         const float* __restrict__ w,
                                         const float* __restrict__ b,
                                         float* __restrict__ out,
                                         int c, int half, int t0) {
    const float* __restrict__ xp = x + c;                      // column base
    const float* __restrict__ wp = w + half * HT * C_DIM + c;
    // this lane stores outputs t0 + k + half (k even): fold +half into the base
    float* __restrict__ opl = out + ((long long)t0 + half) * C_DIM + c;

    // ---- weight-norm: per-half sum of squares, combined across the pair ----
    float wf[HT];
    float ss = 0.0f;
#pragma unroll
    for (int j = 0; j < HT; ++j) {
        wf[j] = wp[j * C_DIM];
        ss = fmaf(wf[j], wf[j], ss);
    }
    ss += __shfl_xor(ss, 32);                                  // full 64-tap norm
    const float inv = 1.0f / fmaxf(sqrtf(ss), 1e-8f);
#pragma unroll
    for (int j = 0; j < HT; ++j) wf[j] = fmaxf(wf[j] * inv, 0.0f);

    const float bv = b[c];
    const float se = (half == 0) ? bv : 0.0f;  // seed of the partial this lane STORES (even k)
    const float so = (half == 0) ? 0.0f : bv;  // seed of the odd-k partial (stored by half1)

    // window base: out[t0+k] uses x[base+k .. base+k+31]; base % 32 == 1
    const int base = t0 - PAD_L + HT * half;

    // ---- warm-up: xbuf[(base+i) & 31] = x[base+i]; (base+i)&31 == (1+i)&31 ----
    float xbuf[HT];
#pragma unroll
    for (int i = 0; i < HT; ++i) {
        const int m = base + i;
        float v = 0.0f;
        if (!GUARD || ((unsigned)m < (unsigned)T_DIM)) v = xp[(long long)m * C_DIM];
        xbuf[(1 + i) & 31] = v;
    }

    // ---- prefetch buffers: values consumed during the CURRENT period ----
    // step kk of period p consumes m = base + 32 + p*32 + kk (inserted after use of oldest)
    float pfA[16], pfB[16];
#pragma unroll
    for (int i = 0; i < 16; ++i) {
        const int m = base + 32 + i;
        float v = 0.0f;
        if (!GUARD || ((unsigned)m < (unsigned)T_DIM)) v = xp[(long long)m * C_DIM];
        pfA[i] = v;
    }
#pragma unroll
    for (int i = 0; i < 16; ++i) {
        const int m = base + 48 + i;
        float v = 0.0f;
        if (!GUARD || ((unsigned)m < (unsigned)T_DIM)) v = xp[(long long)m * C_DIM];
        pfB[i] = v;
    }

    // 32-tap partial for step kk (compile-time kk -> static xbuf slots)
#define PARTIAL(kk, seed, dst)                                                \
    float dst;                                                                \
    {                                                                         \
        float a0 = (seed), a1 = 0.0f;                                         \
        _Pragma("unroll")                                                     \
        for (int j = 0; j < HT; j += 2) {                                     \
            a0 = fmaf(wf[j],     xbuf[((kk) + j + 1) & 31], a0);              \
            a1 = fmaf(wf[j + 1], xbuf[((kk) + j + 2) & 31], a1);              \
        }                                                                     \
        dst = a0 + a1;                                                        \
    }

    // two steps (even kk, kk+1), crosswise exchange, one store per lane-pair half
#define STEP_PAIR(kk)                                                         \
    {                                                                         \
        PARTIAL(kk, se, pe)                                                   \
        xbuf[((kk) + 1) & 31] = ((kk) < 16) ? pfA[(kk) & 15] : pfB[(kk) & 15];\
        PARTIAL((kk) + 1, so, po)                                             \
        xbuf[((kk) + 2) & 31] =                                               \
            (((kk) + 1) < 16) ? pfA[((kk) + 1) & 15] : pfB[((kk) + 1) & 15];  \
        const float snd = (half == 0) ? po : pe;                              \
        const float rcv = __shfl_xor(snd, 32);                                \
        const float res = ((half == 0) ? pe : po) + rcv;                      \
        __builtin_nontemporal_store(res, opl + (long long)(kb + (kk)) * C_DIM);\
    }

#pragma unroll 1
    for (int p = 0; p < NPER; ++p) {
        const int kb = p * 32;
        STEP_PAIR(0)  STEP_PAIR(2)  STEP_PAIR(4)  STEP_PAIR(6)
        STEP_PAIR(8)  STEP_PAIR(10) STEP_PAIR(12) STEP_PAIR(14)
        if (p < NPER - 1) {            // refill pfA for next period (uniform branch)
#pragma unroll
            for (int i = 0; i < 16; ++i) {
                const int m = base + 64 + kb + i;
                float v = 0.0f;
                if (!GUARD || ((unsigned)m < (unsigned)T_DIM)) v = xp[(long long)m * C_DIM];
                pfA[i] = v;
            }
        }
        STEP_PAIR(16) STEP_PAIR(18) STEP_PAIR(20) STEP_PAIR(22)
        STEP_PAIR(24) STEP_PAIR(26) STEP_PAIR(28) STEP_PAIR(30)
        if (p < NPER - 1) {            // refill pfB for next period
#pragma unroll
            for (int i = 0; i < 16; ++i) {
                const int m = base + 80 + kb + i;
                float v = 0.0f;
                if (!GUARD || ((unsigned)m < (unsigned)T_DIM)) v = xp[(long long)m * C_DIM];
                pfB[i] = v;
            }
        }
    }

#undef STEP_PAIR
#undef PARTIAL
}

__global__ __launch_bounds__(256)
void depthwise_fir_kernel(const float* __restrict__ x, const float* __restrict__ w,
                          const float* __restrict__ b, float* __restrict__ out) {
    const int lane = threadIdx.x & 63;
    const int wave = threadIdx.x >> 6;
    // c-blocks on x (fast-varying), t-blocks on y (R11 lesson).
    // lanes 0-31 / 32-63 of a wave: same 32 channels, tap-halves 0 / 1
    const int c    = blockIdx.x * 128 + wave * 32 + (lane & 31);
    const int half = lane >> 5;
    const int t0   = blockIdx.y * KTILE;
    // zero-pad guard only at first/last time tile (block-uniform branch)
    if (blockIdx.y == 0 || blockIdx.y == gridDim.y - 1)
        fir_body<true>(x, w, b, out, c, half, t0);
    else
        fir_body<false>(x, w, b, out, c, half, t0);
}

extern "C" void kernel_launch(void* const* d_in, const int* in_sizes, int n_in,
                              void* d_out, int out_size, void* d_ws, size_t ws_size,
                              hipStream_t stream) {
    const float* x = (const float*)d_in[0];   // [T, C]
    const float* w = (const float*)d_in[1];   // [FW, C]
    const float* b = (const float*)d_in[2];   // [C]
    float* out = (float*)d_out;               // [T, C]

    dim3 grid(C_DIM / 128, T_DIM / KTILE);    // 32 x 32; c-blocks fastest
    dim3 block(256);
    hipLaunchKernelGGL(depthwise_fir_kernel, grid, block, 0, stream, x, w, b, out);
}